// Round 17
// baseline (100.248 us; speedup 1.0000x reference)
//
#include <hip/hip_runtime.h>

typedef unsigned long long ull;

#define NA 147456
#define NB 16
#define NBINS 16384        // top-14 bits of monotonic key
#define CAND_CAP 2048
#define SEG 128
#define NPOST 1000

// ws layout (bytes)
#define OFF_CAND    0                    // 16*2048*8    = 262144
#define OFF_MASK    262144               // 16*1000*16*8 = 2048000 (maskT)
#define OFF_PART    2310144              // 256*8        = 2048
#define OFF_SBOX    2312192              // 16*1000*16   = 256000
#define OFF_SSCORE  2568192              // 16*1000*4    = 64000

__device__ __forceinline__ unsigned mkey(float f) {
  unsigned u = __float_as_uint(f);
  return u ^ ((unsigned)((int)u >> 31) | 0x80000000u);  // monotonic: bigger float -> bigger key
}

// ---------------- K1: fused softmax-reduce + LOCAL top-128 select ------------
__global__ __launch_bounds__(1024) void k_select(const float* __restrict__ labels,
                                                 ull* __restrict__ cand,
                                                 float2* __restrict__ partial) {
  int b = blockIdx.x >> 4, blk = blockIdx.x & 15;
  __shared__ unsigned lh[NBINS];           // 64KB
  __shared__ ull sb[256];
  __shared__ float2 wlds[16];
  __shared__ unsigned wsums[16];
  __shared__ unsigned cntT;
  __shared__ int Tlds;
  int tid = threadIdx.x;
  int lane = tid & 63, wid = tid >> 6;
  for (int i = tid; i < NBINS; i += 1024) lh[i] = 0;
  if (tid < 256) sb[tid] = 0ULL;
  if (tid == 0) cntT = 0;
  __syncthreads();

  const int chunk = NA / 16;               // 9216 floats = 2304 float4
  const float4* row4 = (const float4*)(labels + (size_t)b * NA + blk * chunk);

  float4 v0 = row4[tid];
  float4 v1 = row4[tid + 1024];
  bool extra = tid < 256;
  float4 v2 = extra ? row4[tid + 2048] : make_float4(0.f, 0.f, 0.f, 0.f);

  atomicAdd(&lh[mkey(v0.x) >> 18], 1u);
  atomicAdd(&lh[mkey(v0.y) >> 18], 1u);
  atomicAdd(&lh[mkey(v0.z) >> 18], 1u);
  atomicAdd(&lh[mkey(v0.w) >> 18], 1u);
  atomicAdd(&lh[mkey(v1.x) >> 18], 1u);
  atomicAdd(&lh[mkey(v1.y) >> 18], 1u);
  atomicAdd(&lh[mkey(v1.z) >> 18], 1u);
  atomicAdd(&lh[mkey(v1.w) >> 18], 1u);
  if (extra) {
    atomicAdd(&lh[mkey(v2.x) >> 18], 1u);
    atomicAdd(&lh[mkey(v2.y) >> 18], 1u);
    atomicAdd(&lh[mkey(v2.z) >> 18], 1u);
    atomicAdd(&lh[mkey(v2.w) >> 18], 1u);
  }

  float m = fmaxf(fmaxf(fmaxf(v0.x, v0.y), fmaxf(v0.z, v0.w)),
                  fmaxf(fmaxf(v1.x, v1.y), fmaxf(v1.z, v1.w)));
  if (extra) m = fmaxf(m, fmaxf(fmaxf(v2.x, v2.y), fmaxf(v2.z, v2.w)));
  float s = expf(v0.x - m) + expf(v0.y - m) + expf(v0.z - m) + expf(v0.w - m)
          + expf(v1.x - m) + expf(v1.y - m) + expf(v1.z - m) + expf(v1.w - m);
  if (extra)
    s += expf(v2.x - m) + expf(v2.y - m) + expf(v2.z - m) + expf(v2.w - m);
  for (int off = 32; off > 0; off >>= 1) {
    float m2 = __shfl_down(m, off);
    float s2 = __shfl_down(s, off);
    float M = fmaxf(m, m2);
    s = s * expf(m - M) + s2 * expf(m2 - M);
    m = M;
  }
  if (lane == 0) wlds[wid] = make_float2(m, s);
  __syncthreads();                         // hist complete + wlds complete
  if (tid == 0) {
    float mm = -INFINITY, ss = 0.f;
    for (int i = 0; i < 16; ++i) {
      float2 p = wlds[i];
      float M = fmaxf(mm, p.x);
      ss = ss * expf(mm - M) + p.y * expf(p.x - M);
      mm = M;
    }
    partial[blockIdx.x] = make_float2(mm, ss);
  }

  // descending scan: thread t owns ranks [t*16, t*16+16)
  unsigned lsum = 0;
  unsigned lbin[16];
#pragma unroll
  for (int q = 0; q < 16; ++q) {
    lbin[q] = lh[NBINS - 1 - (tid * 16 + q)];
    lsum += lbin[q];
  }
  unsigned p = lsum;                       // wave inclusive prefix
  for (int d = 1; d < 64; d <<= 1) {
    unsigned t = __shfl_up(p, d);
    if (lane >= d) p += t;
  }
  if (lane == 63) wsums[wid] = p;
  __syncthreads();
  unsigned wexcl = 0;
#pragma unroll
  for (int w = 0; w < 16; ++w) wexcl += (w < wid) ? wsums[w] : 0u;
  unsigned excl = wexcl + p - lsum;
  unsigned incl = excl + lsum;
  if (excl < SEG && incl >= SEG) {         // crossing thread: find T
    unsigned running = excl;
#pragma unroll
    for (int q = 0; q < 16; ++q) {
      unsigned c = lbin[q];
      if (running < SEG && running + c >= SEG) Tlds = NBINS - 1 - (tid * 16 + q);
      running += c;
    }
  }
  __syncthreads();
  unsigned T = (unsigned)Tlds;

  // compact all elements with bin >= T (128..~137 of them) into sb
  {
    float vals[12] = {v0.x, v0.y, v0.z, v0.w, v1.x, v1.y, v1.z, v1.w,
                      v2.x, v2.y, v2.z, v2.w};
    int nv = extra ? 12 : 8;
    for (int c = 0; c < nv; ++c) {
      unsigned kk = mkey(vals[c]);
      if ((kk >> 18) >= T) {
        unsigned pos = atomicAdd(&cntT, 1u);
        int f4i = (c < 4) ? tid : (c < 8) ? (tid + 1024) : (tid + 2048);
        unsigned idx = (unsigned)(blk * chunk + f4i * 4 + (c & 3));
        if (pos < 256) sb[pos] = ((ull)kk << 32) | (unsigned)~idx;
      }
    }
  }
  __syncthreads();

  // wave 0: register bitonic sort of 256 (4 elems/lane), no barriers
  if (tid < 64) {
    ull v[4];
#pragma unroll
    for (int r = 0; r < 4; ++r) v[r] = sb[tid * 4 + r];
#pragma unroll
    for (int k = 2; k <= 256; k <<= 1) {
#pragma unroll
      for (int jl = 256; jl > 0; jl >>= 1) {
        int j = jl >> 1;
        if (j == 0 || j >= k) continue;    // j runs k/2..1
        if (j >= 4) {
          int lx = j >> 2;
#pragma unroll
          for (int r = 0; r < 4; ++r) {
            ull other = __shfl_xor(v[r], lx);
            int e = tid * 4 + r;
            bool up = (e & k) == 0;
            bool lower = (e & j) == 0;
            bool keep_max = (lower == up);
            bool gt = v[r] > other;
            v[r] = (keep_max == gt) ? v[r] : other;
          }
        } else {
#pragma unroll
          for (int r = 0; r < 4; ++r) {
            int rp = r ^ j;
            if (rp > r) {
              int e = tid * 4 + r;
              bool up = (e & k) == 0;
              ull a = v[r], c2 = v[rp];
              if (up ? (a < c2) : (a > c2)) { v[r] = c2; v[rp] = a; }
            }
          }
        }
      }
    }
    if (tid < 32) {
      ull* cb = cand + (size_t)b * CAND_CAP + blk * SEG;
#pragma unroll
      for (int r = 0; r < 4; ++r) cb[tid * 4 + r] = v[r];
    }
  }
}

// ---------------- K2: exact rank via binary search + (m,S) finalize ----------
__global__ __launch_bounds__(512) void k_rank_emit(const ull* __restrict__ cand,
                                                   const float2* __restrict__ partial,
                                                   const float* __restrict__ labels,
                                                   const float* __restrict__ deltas,
                                                   const float4* __restrict__ anchors,
                                                   const float* __restrict__ variances,
                                                   float4* __restrict__ sboxes,
                                                   float* __restrict__ sscores) {
  int b = blockIdx.x >> 2, part = blockIdx.x & 3;
  __shared__ ull sd[CAND_CAP];
  __shared__ float2 msld;
  for (int i = threadIdx.x; i < CAND_CAP; i += 512)
    sd[i] = cand[(size_t)b * CAND_CAP + i];  // 16 sorted (desc) 128-runs
  if (threadIdx.x == 0) {
    float m = -INFINITY, s = 0.f;
    for (int i = 0; i < 16; ++i) {
      float2 pp = partial[b * 16 + i];
      float M = fmaxf(m, pp.x);
      s = s * expf(m - M) + pp.y * expf(pp.x - M);
      m = M;
    }
    msld = make_float2(m, s);
  }
  __syncthreads();

  ull x = sd[part * 512 + threadIdx.x];
  int rank = 0;
#pragma unroll
  for (int t = 0; t < 16; ++t) {
    const ull* run = &sd[t << 7];
    int p = 0;
    if (run[p + 63] > x) p += 64;
    if (run[p + 31] > x) p += 32;
    if (run[p + 15] > x) p += 16;
    if (run[p + 7]  > x) p += 8;
    if (run[p + 3]  > x) p += 4;
    if (run[p + 1]  > x) p += 2;
    if (run[p]      > x) p += 1;
    rank += p;
  }
  if (rank >= NPOST) return;

  unsigned idx = ~(unsigned)(x & 0xFFFFFFFFu);
  float2 mt = msld;
  float lab = labels[(size_t)b * NA + idx];
  float score = expf(lab - mt.x) / mt.y;

  float4 an = anchors[idx];                  // [y1,x1,y2,x2]
  float aw = an.w - an.y;
  float ah = an.z - an.x;
  float acx = an.y + 0.5f * aw;
  float acy = an.x + 0.5f * ah;
  float4 dl = *(const float4*)(deltas + ((size_t)b * NA + idx) * 4);
  float4 var = *(const float4*)variances;
  float t0 = dl.x * var.x, t1 = dl.y * var.y, t2 = dl.z * var.z, t3 = dl.w * var.w;
  float bw = expf(t3) * aw;
  float bh = expf(t2) * ah;
  float bcx = t1 * aw + acx;
  float bcy = t0 * ah + acy;
  float y1 = bcy - 0.5f * bh, x1 = bcx - 0.5f * bw;
  float y2 = bh + y1, x2 = bw + x1;
  sboxes[(size_t)b * NPOST + rank] = make_float4(y1, x1, y2, x2);
  sscores[(size_t)b * NPOST + rank] = score;
}

// ---------------- K3: pairwise IoU, TRANSPOSED (lower-tri) bitmask -----------
// Early-exit: word w of column i is provably zero when w*64 >= i (lower-tri).
__global__ __launch_bounds__(256) void k_mask(const float4* __restrict__ sboxes,
                                              ull* __restrict__ maskT) {
  int b = blockIdx.x / 63, tile = blockIdx.x % 63;
  __shared__ float4 bx[NPOST];               // 16KB
  for (int j = threadIdx.x; j < NPOST; j += 256) bx[j] = sboxes[(size_t)b * NPOST + j];
  __syncthreads();
  int il = threadIdx.x >> 4, w = threadIdx.x & 15;
  int i = tile * 16 + il;
  if (i < NPOST) {
    ull bits = 0;
    if ((w << 6) < i) {                      // some j = w*64+jb can be < i
      float4 bi = bx[i];
      float ay1 = bi.x, ax1 = bi.y, ay2 = bi.z, ax2 = bi.w;
      float areai = (ay2 - ay1) * (ax2 - ax1);
      for (int jj = 0; jj < 64; ++jj) {
        int jb = (jj + w) & 63;              // skew to dodge LDS bank conflicts
        int j = (w << 6) + jb;
        if (j < i) {                         // lower-tri: rows j that suppress col i
          float4 bj = bx[j];
          float areaj = (bj.z - bj.x) * (bj.w - bj.y);
          float iy1 = fmaxf(ay1, bj.x), ix1 = fmaxf(ax1, bj.y);
          float iy2 = fminf(ay2, bj.z), ix2 = fminf(ax2, bj.w);
          float inter = fmaxf(iy2 - iy1, 0.f) * fmaxf(ix2 - ix1, 0.f);
          float uni = areai + areaj - inter;
          float iou = inter / fmaxf(uni, 1e-9f);
          if (iou > 0.7f) bits |= (1ull << jb);
        }
      }
    }
    maskT[((size_t)b * NPOST + i) * 16 + w] = bits;   // always write (nms reads)
  }
}

// ---------------- K4: greedy NMS, LDS-staged mask, rolled ballot chain -------
// Stage the batch's full 128KB maskT into padded LDS (stride 17 -> <=4-way
// bank conflicts) with all 4 waves, then wave 0 runs the 16-phase chain from
// LDS (~120cy latency vs ~900cy HBM) with a ROLLED w-loop (small code, no
// icache streaming, no prefetch registers). ks broadcast via keep_lds.
__global__ __launch_bounds__(256, 1) void k_nms(const ull* __restrict__ maskT,
                                                const float4* __restrict__ sboxes,
                                                const float* __restrict__ sscores,
                                                float* __restrict__ out) {
  int b = blockIdx.x;
  __shared__ ull mt[NPOST * 17];             // 136KB padded column-major mask
  __shared__ ull keep_lds[16];
  __shared__ int pref[17];
  int tid = threadIdx.x;

  const ull* MT = maskT + (size_t)b * NPOST * 16;
  for (int e = tid; e < NPOST * 16; e += 256)
    mt[(e >> 4) * 17 + (e & 15)] = MT[e];    // coalesced global read
  __syncthreads();

  if (tid < 64) {
    int lane = tid;
#pragma unroll 1
    for (int w = 0; w < 16; ++w) {
      int c = w * 64 + lane; if (c > NPOST - 1) c = NPOST - 1;
      const ull* col = &mt[c * 17];
      ull acc = 0;
#pragma unroll
      for (int k = 0; k < 15; ++k)
        acc |= (k < w) ? (col[k] & keep_lds[k]) : 0ull;
      ull rm0 = (w == 0) ? 0ull : __ballot(acc != 0ull);
      ull qT = col[w];
      unsigned qlo = (unsigned)qT, qhi = (unsigned)(qT >> 32);

      ull kmask = 0, supp = rm0;
#pragma unroll
      for (int bt = 0; bt < 4; ++bt) {
        ull rows[16];
        unsigned qd = (bt < 2) ? qlo : qhi;
#pragma unroll
        for (int r = 0; r < 16; ++r)
          rows[r] = __ballot(((qd >> ((bt & 1) * 16 + r)) & 1u) != 0u);
#pragma unroll
        for (int r = 0; r < 16; ++r) {
          int rr = bt * 16 + r;
          bool kp = ((supp >> rr) & 1ull) == 0ull;
          kmask |= kp ? (1ull << rr) : 0ull;
          supp  |= kp ? rows[r] : 0ull;
        }
      }
      if (w == 15) kmask &= (1ull << 40) - 1;   // boxes 1000..1023 invalid
      if (lane == 0) keep_lds[w] = kmask;
    }

    if (lane == 0) {
      int a = 0;
      for (int w = 0; w < 16; ++w) { pref[w] = a; a += __popcll(keep_lds[w]); }
      pref[16] = a;
    }
  }
  __syncthreads();

  int total = pref[16];
  float4* ob = (float4*)out;                 // boxes: 16*1000 float4
  float* os = out + (size_t)NB * NPOST * 4;  // scores: 16*1000 floats
  for (int r = tid; r < NPOST; r += 256) {
    if (r >= total) {
      ob[(size_t)b * NPOST + r] = make_float4(0.f, 0.f, 0.f, 0.f);
      os[(size_t)b * NPOST + r] = 0.f;
    }
  }
  for (int r = tid; r < NPOST; r += 256) {
    int w = r >> 6, bb = r & 63;
    ull kw = keep_lds[w];
    if ((kw >> bb) & 1ull) {
      int pos = pref[w] + __popcll(bb ? (kw & ((1ull << bb) - 1)) : 0ull);
      ob[(size_t)b * NPOST + pos] = sboxes[(size_t)b * NPOST + r];
      os[(size_t)b * NPOST + pos] = sscores[(size_t)b * NPOST + r];
    }
  }
}

extern "C" void kernel_launch(void* const* d_in, const int* in_sizes, int n_in,
                              void* d_out, int out_size, void* d_ws, size_t ws_size,
                              hipStream_t stream) {
  const float* deltas    = (const float*)d_in[0];
  const float* labels    = (const float*)d_in[1];
  const float* anchors   = (const float*)d_in[2];
  const float* variances = (const float*)d_in[3];

  char* ws = (char*)d_ws;
  ull*     cand    = (ull*)(ws + OFF_CAND);
  ull*     maskT   = (ull*)(ws + OFF_MASK);
  float2*  partial = (float2*)(ws + OFF_PART);
  float4*  sboxes  = (float4*)(ws + OFF_SBOX);
  float*   sscores = (float*)(ws + OFF_SSCORE);

  k_select<<<NB * 16, 1024, 0, stream>>>(labels, cand, partial);
  k_rank_emit<<<NB * 4, 512, 0, stream>>>(cand, partial, labels, deltas,
                                          (const float4*)anchors, variances,
                                          sboxes, sscores);
  k_mask<<<NB * 63, 256, 0, stream>>>(sboxes, maskT);
  k_nms<<<NB, 256, 0, stream>>>(maskT, sboxes, sscores, (float*)d_out);
}

// Round 18
// 90.510 us; speedup vs baseline: 1.1076x; 1.1076x over previous
//
#include <hip/hip_runtime.h>

typedef unsigned long long ull;

#define NA 147456
#define NB 16
#define NBINS 16384        // top-14 bits of monotonic key
#define CAND_CAP 2048
#define SEG 128
#define NPOST 1000

// ws layout (bytes)
#define OFF_CAND    0                    // 16*2048*8    = 262144
#define OFF_MASK    262144               // 16*1000*16*8 = 2048000 (maskT)
#define OFF_PART    2310144              // 256*8        = 2048
#define OFF_SBOX    2312192              // 16*1000*16   = 256000
#define OFF_SSCORE  2568192              // 16*1000*4    = 64000

__device__ __forceinline__ unsigned mkey(float f) {
  unsigned u = __float_as_uint(f);
  return u ^ ((unsigned)((int)u >> 31) | 0x80000000u);  // monotonic: bigger float -> bigger key
}

// ---------------- K1: fused softmax-reduce + LOCAL top-128 select ------------
__global__ __launch_bounds__(1024) void k_select(const float* __restrict__ labels,
                                                 ull* __restrict__ cand,
                                                 float2* __restrict__ partial) {
  int b = blockIdx.x >> 4, blk = blockIdx.x & 15;
  __shared__ unsigned lh[NBINS];           // 64KB
  __shared__ ull sb[256];
  __shared__ float2 wlds[16];
  __shared__ unsigned wsums[16];
  __shared__ unsigned cntT;
  __shared__ int Tlds;
  int tid = threadIdx.x;
  int lane = tid & 63, wid = tid >> 6;
  for (int i = tid; i < NBINS; i += 1024) lh[i] = 0;
  if (tid < 256) sb[tid] = 0ULL;
  if (tid == 0) cntT = 0;
  __syncthreads();

  const int chunk = NA / 16;               // 9216 floats = 2304 float4
  const float4* row4 = (const float4*)(labels + (size_t)b * NA + blk * chunk);

  float4 v0 = row4[tid];
  float4 v1 = row4[tid + 1024];
  bool extra = tid < 256;
  float4 v2 = extra ? row4[tid + 2048] : make_float4(0.f, 0.f, 0.f, 0.f);

  atomicAdd(&lh[mkey(v0.x) >> 18], 1u);
  atomicAdd(&lh[mkey(v0.y) >> 18], 1u);
  atomicAdd(&lh[mkey(v0.z) >> 18], 1u);
  atomicAdd(&lh[mkey(v0.w) >> 18], 1u);
  atomicAdd(&lh[mkey(v1.x) >> 18], 1u);
  atomicAdd(&lh[mkey(v1.y) >> 18], 1u);
  atomicAdd(&lh[mkey(v1.z) >> 18], 1u);
  atomicAdd(&lh[mkey(v1.w) >> 18], 1u);
  if (extra) {
    atomicAdd(&lh[mkey(v2.x) >> 18], 1u);
    atomicAdd(&lh[mkey(v2.y) >> 18], 1u);
    atomicAdd(&lh[mkey(v2.z) >> 18], 1u);
    atomicAdd(&lh[mkey(v2.w) >> 18], 1u);
  }

  float m = fmaxf(fmaxf(fmaxf(v0.x, v0.y), fmaxf(v0.z, v0.w)),
                  fmaxf(fmaxf(v1.x, v1.y), fmaxf(v1.z, v1.w)));
  if (extra) m = fmaxf(m, fmaxf(fmaxf(v2.x, v2.y), fmaxf(v2.z, v2.w)));
  float s = expf(v0.x - m) + expf(v0.y - m) + expf(v0.z - m) + expf(v0.w - m)
          + expf(v1.x - m) + expf(v1.y - m) + expf(v1.z - m) + expf(v1.w - m);
  if (extra)
    s += expf(v2.x - m) + expf(v2.y - m) + expf(v2.z - m) + expf(v2.w - m);
  for (int off = 32; off > 0; off >>= 1) {
    float m2 = __shfl_down(m, off);
    float s2 = __shfl_down(s, off);
    float M = fmaxf(m, m2);
    s = s * expf(m - M) + s2 * expf(m2 - M);
    m = M;
  }
  if (lane == 0) wlds[wid] = make_float2(m, s);
  __syncthreads();                         // hist complete + wlds complete
  if (tid == 0) {
    float mm = -INFINITY, ss = 0.f;
    for (int i = 0; i < 16; ++i) {
      float2 p = wlds[i];
      float M = fmaxf(mm, p.x);
      ss = ss * expf(mm - M) + p.y * expf(p.x - M);
      mm = M;
    }
    partial[blockIdx.x] = make_float2(mm, ss);
  }

  // descending scan: thread t owns ranks [t*16, t*16+16)
  unsigned lsum = 0;
  unsigned lbin[16];
#pragma unroll
  for (int q = 0; q < 16; ++q) {
    lbin[q] = lh[NBINS - 1 - (tid * 16 + q)];
    lsum += lbin[q];
  }
  unsigned p = lsum;                       // wave inclusive prefix
  for (int d = 1; d < 64; d <<= 1) {
    unsigned t = __shfl_up(p, d);
    if (lane >= d) p += t;
  }
  if (lane == 63) wsums[wid] = p;
  __syncthreads();
  unsigned wexcl = 0;
#pragma unroll
  for (int w = 0; w < 16; ++w) wexcl += (w < wid) ? wsums[w] : 0u;
  unsigned excl = wexcl + p - lsum;
  unsigned incl = excl + lsum;
  if (excl < SEG && incl >= SEG) {         // crossing thread: find T
    unsigned running = excl;
#pragma unroll
    for (int q = 0; q < 16; ++q) {
      unsigned c = lbin[q];
      if (running < SEG && running + c >= SEG) Tlds = NBINS - 1 - (tid * 16 + q);
      running += c;
    }
  }
  __syncthreads();
  unsigned T = (unsigned)Tlds;

  // compact all elements with bin >= T (128..~137 of them) into sb
  {
    float vals[12] = {v0.x, v0.y, v0.z, v0.w, v1.x, v1.y, v1.z, v1.w,
                      v2.x, v2.y, v2.z, v2.w};
    int nv = extra ? 12 : 8;
    for (int c = 0; c < nv; ++c) {
      unsigned kk = mkey(vals[c]);
      if ((kk >> 18) >= T) {
        unsigned pos = atomicAdd(&cntT, 1u);
        int f4i = (c < 4) ? tid : (c < 8) ? (tid + 1024) : (tid + 2048);
        unsigned idx = (unsigned)(blk * chunk + f4i * 4 + (c & 3));
        if (pos < 256) sb[pos] = ((ull)kk << 32) | (unsigned)~idx;
      }
    }
  }
  __syncthreads();

  // wave 0: register bitonic sort of 256 (4 elems/lane), no barriers
  if (tid < 64) {
    ull v[4];
#pragma unroll
    for (int r = 0; r < 4; ++r) v[r] = sb[tid * 4 + r];
#pragma unroll
    for (int k = 2; k <= 256; k <<= 1) {
#pragma unroll
      for (int jl = 256; jl > 0; jl >>= 1) {
        int j = jl >> 1;
        if (j == 0 || j >= k) continue;    // j runs k/2..1
        if (j >= 4) {
          int lx = j >> 2;
#pragma unroll
          for (int r = 0; r < 4; ++r) {
            ull other = __shfl_xor(v[r], lx);
            int e = tid * 4 + r;
            bool up = (e & k) == 0;
            bool lower = (e & j) == 0;
            bool keep_max = (lower == up);
            bool gt = v[r] > other;
            v[r] = (keep_max == gt) ? v[r] : other;
          }
        } else {
#pragma unroll
          for (int r = 0; r < 4; ++r) {
            int rp = r ^ j;
            if (rp > r) {
              int e = tid * 4 + r;
              bool up = (e & k) == 0;
              ull a = v[r], c2 = v[rp];
              if (up ? (a < c2) : (a > c2)) { v[r] = c2; v[rp] = a; }
            }
          }
        }
      }
    }
    if (tid < 32) {
      ull* cb = cand + (size_t)b * CAND_CAP + blk * SEG;
#pragma unroll
      for (int r = 0; r < 4; ++r) cb[tid * 4 + r] = v[r];
    }
  }
}

// ---------------- K2: exact rank via binary search + (m,S) finalize ----------
__global__ __launch_bounds__(512) void k_rank_emit(const ull* __restrict__ cand,
                                                   const float2* __restrict__ partial,
                                                   const float* __restrict__ labels,
                                                   const float* __restrict__ deltas,
                                                   const float4* __restrict__ anchors,
                                                   const float* __restrict__ variances,
                                                   float4* __restrict__ sboxes,
                                                   float* __restrict__ sscores) {
  int b = blockIdx.x >> 2, part = blockIdx.x & 3;
  __shared__ ull sd[CAND_CAP];
  __shared__ float2 msld;
  for (int i = threadIdx.x; i < CAND_CAP; i += 512)
    sd[i] = cand[(size_t)b * CAND_CAP + i];  // 16 sorted (desc) 128-runs
  if (threadIdx.x == 0) {
    float m = -INFINITY, s = 0.f;
    for (int i = 0; i < 16; ++i) {
      float2 pp = partial[b * 16 + i];
      float M = fmaxf(m, pp.x);
      s = s * expf(m - M) + pp.y * expf(pp.x - M);
      m = M;
    }
    msld = make_float2(m, s);
  }
  __syncthreads();

  ull x = sd[part * 512 + threadIdx.x];
  int rank = 0;
#pragma unroll
  for (int t = 0; t < 16; ++t) {
    const ull* run = &sd[t << 7];
    int p = 0;
    if (run[p + 63] > x) p += 64;
    if (run[p + 31] > x) p += 32;
    if (run[p + 15] > x) p += 16;
    if (run[p + 7]  > x) p += 8;
    if (run[p + 3]  > x) p += 4;
    if (run[p + 1]  > x) p += 2;
    if (run[p]      > x) p += 1;
    rank += p;
  }
  if (rank >= NPOST) return;

  unsigned idx = ~(unsigned)(x & 0xFFFFFFFFu);
  float2 mt = msld;
  float lab = labels[(size_t)b * NA + idx];
  float score = expf(lab - mt.x) / mt.y;

  float4 an = anchors[idx];                  // [y1,x1,y2,x2]
  float aw = an.w - an.y;
  float ah = an.z - an.x;
  float acx = an.y + 0.5f * aw;
  float acy = an.x + 0.5f * ah;
  float4 dl = *(const float4*)(deltas + ((size_t)b * NA + idx) * 4);
  float4 var = *(const float4*)variances;
  float t0 = dl.x * var.x, t1 = dl.y * var.y, t2 = dl.z * var.z, t3 = dl.w * var.w;
  float bw = expf(t3) * aw;
  float bh = expf(t2) * ah;
  float bcx = t1 * aw + acx;
  float bcy = t0 * ah + acy;
  float y1 = bcy - 0.5f * bh, x1 = bcx - 0.5f * bw;
  float y2 = bh + y1, x2 = bw + x1;
  sboxes[(size_t)b * NPOST + rank] = make_float4(y1, x1, y2, x2);
  sscores[(size_t)b * NPOST + rank] = score;
}

// ---------------- K3: pairwise IoU, TRANSPOSED (lower-tri) bitmask -----------
// Early-exit: word w of column i is provably zero when w*64 >= i (lower-tri).
__global__ __launch_bounds__(256) void k_mask(const float4* __restrict__ sboxes,
                                              ull* __restrict__ maskT) {
  int b = blockIdx.x / 63, tile = blockIdx.x % 63;
  __shared__ float4 bx[NPOST];               // 16KB
  for (int j = threadIdx.x; j < NPOST; j += 256) bx[j] = sboxes[(size_t)b * NPOST + j];
  __syncthreads();
  int il = threadIdx.x >> 4, w = threadIdx.x & 15;
  int i = tile * 16 + il;
  if (i < NPOST) {
    ull bits = 0;
    if ((w << 6) < i) {                      // some j = w*64+jb can be < i
      float4 bi = bx[i];
      float ay1 = bi.x, ax1 = bi.y, ay2 = bi.z, ax2 = bi.w;
      float areai = (ay2 - ay1) * (ax2 - ax1);
      for (int jj = 0; jj < 64; ++jj) {
        int jb = (jj + w) & 63;              // skew to dodge LDS bank conflicts
        int j = (w << 6) + jb;
        if (j < i) {                         // lower-tri: rows j that suppress col i
          float4 bj = bx[j];
          float areaj = (bj.z - bj.x) * (bj.w - bj.y);
          float iy1 = fmaxf(ay1, bj.x), ix1 = fmaxf(ax1, bj.y);
          float iy2 = fminf(ay2, bj.z), ix2 = fminf(ax2, bj.w);
          float inter = fmaxf(iy2 - iy1, 0.f) * fmaxf(ix2 - ix1, 0.f);
          float uni = areai + areaj - inter;
          float iou = inter / fmaxf(uni, 1e-9f);
          if (iou > 0.7f) bits |= (1ull << jb);
        }
      }
    }
    maskT[((size_t)b * NPOST + i) * 16 + w] = bits;   // always write (nms reads)
  }
}

// ---------------- K4: greedy NMS, direct L2 reads, rolled ballot chain -------
// No staging (R17 lesson: stage serialization > chain savings). Per phase,
// each lane loads its column's 16 words as 8x ulonglong2 (128B contiguous,
// coalesced, L2-resident). qT extracted via static-unrolled select (no
// runtime indexing -> no scratch). keep history broadcast from keep_lds.
__global__ __launch_bounds__(256, 1) void k_nms(const ull* __restrict__ maskT,
                                                const float4* __restrict__ sboxes,
                                                const float* __restrict__ sscores,
                                                float* __restrict__ out) {
  int b = blockIdx.x;
  __shared__ ull keep_lds[16];
  __shared__ int pref[17];
  int tid = threadIdx.x;

  const ull* MT = maskT + (size_t)b * NPOST * 16;

  if (tid < 64) {
    int lane = tid;
#pragma unroll 1
    for (int w = 0; w < 16; ++w) {
      int c = w * 64 + lane; if (c > NPOST - 1) c = NPOST - 1;
      ull col[16];
      {
        const ulonglong2* cg = (const ulonglong2*)(MT + (size_t)c * 16);
#pragma unroll
        for (int k = 0; k < 8; ++k) {
          ulonglong2 t = cg[k];
          col[2 * k] = t.x; col[2 * k + 1] = t.y;
        }
      }
      ull acc = 0, qT = col[15];
#pragma unroll
      for (int k = 0; k < 15; ++k) {
        if (k == w) qT = col[k];             // static k vs dynamic w: select
        acc |= (k < w) ? (col[k] & keep_lds[k]) : 0ull;
      }
      ull rm0 = (w == 0) ? 0ull : __ballot(acc != 0ull);
      unsigned qlo = (unsigned)qT, qhi = (unsigned)(qT >> 32);

      ull kmask = 0, supp = rm0;
#pragma unroll
      for (int bt = 0; bt < 4; ++bt) {
        ull rows[16];
        unsigned qd = (bt < 2) ? qlo : qhi;
#pragma unroll
        for (int r = 0; r < 16; ++r)
          rows[r] = __ballot(((qd >> ((bt & 1) * 16 + r)) & 1u) != 0u);
#pragma unroll
        for (int r = 0; r < 16; ++r) {
          int rr = bt * 16 + r;
          bool kp = ((supp >> rr) & 1ull) == 0ull;
          kmask |= kp ? (1ull << rr) : 0ull;
          supp  |= kp ? rows[r] : 0ull;
        }
      }
      if (w == 15) kmask &= (1ull << 40) - 1;   // boxes 1000..1023 invalid
      if (lane == 0) keep_lds[w] = kmask;
    }

    if (lane == 0) {
      int a = 0;
      for (int w = 0; w < 16; ++w) { pref[w] = a; a += __popcll(keep_lds[w]); }
      pref[16] = a;
    }
  }
  __syncthreads();

  int total = pref[16];
  float4* ob = (float4*)out;                 // boxes: 16*1000 float4
  float* os = out + (size_t)NB * NPOST * 4;  // scores: 16*1000 floats
  for (int r = tid; r < NPOST; r += 256) {
    if (r >= total) {
      ob[(size_t)b * NPOST + r] = make_float4(0.f, 0.f, 0.f, 0.f);
      os[(size_t)b * NPOST + r] = 0.f;
    }
  }
  for (int r = tid; r < NPOST; r += 256) {
    int w = r >> 6, bb = r & 63;
    ull kw = keep_lds[w];
    if ((kw >> bb) & 1ull) {
      int pos = pref[w] + __popcll(bb ? (kw & ((1ull << bb) - 1)) : 0ull);
      ob[(size_t)b * NPOST + pos] = sboxes[(size_t)b * NPOST + r];
      os[(size_t)b * NPOST + pos] = sscores[(size_t)b * NPOST + r];
    }
  }
}

extern "C" void kernel_launch(void* const* d_in, const int* in_sizes, int n_in,
                              void* d_out, int out_size, void* d_ws, size_t ws_size,
                              hipStream_t stream) {
  const float* deltas    = (const float*)d_in[0];
  const float* labels    = (const float*)d_in[1];
  const float* anchors   = (const float*)d_in[2];
  const float* variances = (const float*)d_in[3];

  char* ws = (char*)d_ws;
  ull*     cand    = (ull*)(ws + OFF_CAND);
  ull*     maskT   = (ull*)(ws + OFF_MASK);
  float2*  partial = (float2*)(ws + OFF_PART);
  float4*  sboxes  = (float4*)(ws + OFF_SBOX);
  float*   sscores = (float*)(ws + OFF_SSCORE);

  k_select<<<NB * 16, 1024, 0, stream>>>(labels, cand, partial);
  k_rank_emit<<<NB * 4, 512, 0, stream>>>(cand, partial, labels, deltas,
                                          (const float4*)anchors, variances,
                                          sboxes, sscores);
  k_mask<<<NB * 63, 256, 0, stream>>>(sboxes, maskT);
  k_nms<<<NB, 256, 0, stream>>>(maskT, sboxes, sscores, (float*)d_out);
}

// Round 19
// 87.246 us; speedup vs baseline: 1.1490x; 1.0374x over previous
//
#include <hip/hip_runtime.h>

typedef unsigned long long ull;

#define NA 147456
#define NB 16
#define NBINS 16384        // top-14 bits of monotonic key
#define CAND_CAP 2048
#define SEG 128
#define NPOST 1000
#define CSTRIDE 17         // padded column stride (u64) -> 4-way banks max

// ws layout (bytes)
#define OFF_CAND    0                    // 16*2048*8    = 262144
#define OFF_MASK    262144               // 16*1000*16*8 = 2048000 (maskT)
#define OFF_PART    2310144              // 256*8        = 2048
#define OFF_SBOX    2312192              // 16*1000*16   = 256000
#define OFF_SSCORE  2568192              // 16*1000*4    = 64000

__device__ __forceinline__ unsigned mkey(float f) {
  unsigned u = __float_as_uint(f);
  return u ^ ((unsigned)((int)u >> 31) | 0x80000000u);  // monotonic: bigger float -> bigger key
}

// ---------------- K1: fused softmax-reduce + LOCAL top-128 select ------------
__global__ __launch_bounds__(1024) void k_select(const float* __restrict__ labels,
                                                 ull* __restrict__ cand,
                                                 float2* __restrict__ partial) {
  int b = blockIdx.x >> 4, blk = blockIdx.x & 15;
  __shared__ unsigned lh[NBINS];           // 64KB
  __shared__ ull sb[256];
  __shared__ float2 wlds[16];
  __shared__ unsigned wsums[16];
  __shared__ unsigned cntT;
  __shared__ int Tlds;
  int tid = threadIdx.x;
  int lane = tid & 63, wid = tid >> 6;
  for (int i = tid; i < NBINS; i += 1024) lh[i] = 0;
  if (tid < 256) sb[tid] = 0ULL;
  if (tid == 0) cntT = 0;
  __syncthreads();

  const int chunk = NA / 16;               // 9216 floats = 2304 float4
  const float4* row4 = (const float4*)(labels + (size_t)b * NA + blk * chunk);

  float4 v0 = row4[tid];
  float4 v1 = row4[tid + 1024];
  bool extra = tid < 256;
  float4 v2 = extra ? row4[tid + 2048] : make_float4(0.f, 0.f, 0.f, 0.f);

  atomicAdd(&lh[mkey(v0.x) >> 18], 1u);
  atomicAdd(&lh[mkey(v0.y) >> 18], 1u);
  atomicAdd(&lh[mkey(v0.z) >> 18], 1u);
  atomicAdd(&lh[mkey(v0.w) >> 18], 1u);
  atomicAdd(&lh[mkey(v1.x) >> 18], 1u);
  atomicAdd(&lh[mkey(v1.y) >> 18], 1u);
  atomicAdd(&lh[mkey(v1.z) >> 18], 1u);
  atomicAdd(&lh[mkey(v1.w) >> 18], 1u);
  if (extra) {
    atomicAdd(&lh[mkey(v2.x) >> 18], 1u);
    atomicAdd(&lh[mkey(v2.y) >> 18], 1u);
    atomicAdd(&lh[mkey(v2.z) >> 18], 1u);
    atomicAdd(&lh[mkey(v2.w) >> 18], 1u);
  }

  float m = fmaxf(fmaxf(fmaxf(v0.x, v0.y), fmaxf(v0.z, v0.w)),
                  fmaxf(fmaxf(v1.x, v1.y), fmaxf(v1.z, v1.w)));
  if (extra) m = fmaxf(m, fmaxf(fmaxf(v2.x, v2.y), fmaxf(v2.z, v2.w)));
  float s = expf(v0.x - m) + expf(v0.y - m) + expf(v0.z - m) + expf(v0.w - m)
          + expf(v1.x - m) + expf(v1.y - m) + expf(v1.z - m) + expf(v1.w - m);
  if (extra)
    s += expf(v2.x - m) + expf(v2.y - m) + expf(v2.z - m) + expf(v2.w - m);
  for (int off = 32; off > 0; off >>= 1) {
    float m2 = __shfl_down(m, off);
    float s2 = __shfl_down(s, off);
    float M = fmaxf(m, m2);
    s = s * expf(m - M) + s2 * expf(m2 - M);
    m = M;
  }
  if (lane == 0) wlds[wid] = make_float2(m, s);
  __syncthreads();                         // hist complete + wlds complete
  if (tid == 0) {
    float mm = -INFINITY, ss = 0.f;
    for (int i = 0; i < 16; ++i) {
      float2 p = wlds[i];
      float M = fmaxf(mm, p.x);
      ss = ss * expf(mm - M) + p.y * expf(p.x - M);
      mm = M;
    }
    partial[blockIdx.x] = make_float2(mm, ss);
  }

  // descending scan: thread t owns ranks [t*16, t*16+16)
  unsigned lsum = 0;
  unsigned lbin[16];
#pragma unroll
  for (int q = 0; q < 16; ++q) {
    lbin[q] = lh[NBINS - 1 - (tid * 16 + q)];
    lsum += lbin[q];
  }
  unsigned p = lsum;                       // wave inclusive prefix
  for (int d = 1; d < 64; d <<= 1) {
    unsigned t = __shfl_up(p, d);
    if (lane >= d) p += t;
  }
  if (lane == 63) wsums[wid] = p;
  __syncthreads();
  unsigned wexcl = 0;
#pragma unroll
  for (int w = 0; w < 16; ++w) wexcl += (w < wid) ? wsums[w] : 0u;
  unsigned excl = wexcl + p - lsum;
  unsigned incl = excl + lsum;
  if (excl < SEG && incl >= SEG) {         // crossing thread: find T
    unsigned running = excl;
#pragma unroll
    for (int q = 0; q < 16; ++q) {
      unsigned c = lbin[q];
      if (running < SEG && running + c >= SEG) Tlds = NBINS - 1 - (tid * 16 + q);
      running += c;
    }
  }
  __syncthreads();
  unsigned T = (unsigned)Tlds;

  // compact all elements with bin >= T (128..~137 of them) into sb
  {
    float vals[12] = {v0.x, v0.y, v0.z, v0.w, v1.x, v1.y, v1.z, v1.w,
                      v2.x, v2.y, v2.z, v2.w};
    int nv = extra ? 12 : 8;
    for (int c = 0; c < nv; ++c) {
      unsigned kk = mkey(vals[c]);
      if ((kk >> 18) >= T) {
        unsigned pos = atomicAdd(&cntT, 1u);
        int f4i = (c < 4) ? tid : (c < 8) ? (tid + 1024) : (tid + 2048);
        unsigned idx = (unsigned)(blk * chunk + f4i * 4 + (c & 3));
        if (pos < 256) sb[pos] = ((ull)kk << 32) | (unsigned)~idx;
      }
    }
  }
  __syncthreads();

  // wave 0: register bitonic sort of 256 (4 elems/lane), no barriers
  if (tid < 64) {
    ull v[4];
#pragma unroll
    for (int r = 0; r < 4; ++r) v[r] = sb[tid * 4 + r];
#pragma unroll
    for (int k = 2; k <= 256; k <<= 1) {
#pragma unroll
      for (int jl = 256; jl > 0; jl >>= 1) {
        int j = jl >> 1;
        if (j == 0 || j >= k) continue;    // j runs k/2..1
        if (j >= 4) {
          int lx = j >> 2;
#pragma unroll
          for (int r = 0; r < 4; ++r) {
            ull other = __shfl_xor(v[r], lx);
            int e = tid * 4 + r;
            bool up = (e & k) == 0;
            bool lower = (e & j) == 0;
            bool keep_max = (lower == up);
            bool gt = v[r] > other;
            v[r] = (keep_max == gt) ? v[r] : other;
          }
        } else {
#pragma unroll
          for (int r = 0; r < 4; ++r) {
            int rp = r ^ j;
            if (rp > r) {
              int e = tid * 4 + r;
              bool up = (e & k) == 0;
              ull a = v[r], c2 = v[rp];
              if (up ? (a < c2) : (a > c2)) { v[r] = c2; v[rp] = a; }
            }
          }
        }
      }
    }
    if (tid < 32) {
      ull* cb = cand + (size_t)b * CAND_CAP + blk * SEG;
#pragma unroll
      for (int r = 0; r < 4; ++r) cb[tid * 4 + r] = v[r];
    }
  }
}

// ---------------- K2: exact rank via binary search + (m,S) finalize ----------
__global__ __launch_bounds__(512) void k_rank_emit(const ull* __restrict__ cand,
                                                   const float2* __restrict__ partial,
                                                   const float* __restrict__ labels,
                                                   const float* __restrict__ deltas,
                                                   const float4* __restrict__ anchors,
                                                   const float* __restrict__ variances,
                                                   float4* __restrict__ sboxes,
                                                   float* __restrict__ sscores) {
  int b = blockIdx.x >> 2, part = blockIdx.x & 3;
  __shared__ ull sd[CAND_CAP];
  __shared__ float2 msld;
  for (int i = threadIdx.x; i < CAND_CAP; i += 512)
    sd[i] = cand[(size_t)b * CAND_CAP + i];  // 16 sorted (desc) 128-runs
  if (threadIdx.x == 0) {
    float m = -INFINITY, s = 0.f;
    for (int i = 0; i < 16; ++i) {
      float2 pp = partial[b * 16 + i];
      float M = fmaxf(m, pp.x);
      s = s * expf(m - M) + pp.y * expf(pp.x - M);
      m = M;
    }
    msld = make_float2(m, s);
  }
  __syncthreads();

  ull x = sd[part * 512 + threadIdx.x];
  int rank = 0;
#pragma unroll
  for (int t = 0; t < 16; ++t) {
    const ull* run = &sd[t << 7];
    int p = 0;
    if (run[p + 63] > x) p += 64;
    if (run[p + 31] > x) p += 32;
    if (run[p + 15] > x) p += 16;
    if (run[p + 7]  > x) p += 8;
    if (run[p + 3]  > x) p += 4;
    if (run[p + 1]  > x) p += 2;
    if (run[p]      > x) p += 1;
    rank += p;
  }
  if (rank >= NPOST) return;

  unsigned idx = ~(unsigned)(x & 0xFFFFFFFFu);
  float2 mt = msld;
  float lab = labels[(size_t)b * NA + idx];
  float score = expf(lab - mt.x) / mt.y;

  float4 an = anchors[idx];                  // [y1,x1,y2,x2]
  float aw = an.w - an.y;
  float ah = an.z - an.x;
  float acx = an.y + 0.5f * aw;
  float acy = an.x + 0.5f * ah;
  float4 dl = *(const float4*)(deltas + ((size_t)b * NA + idx) * 4);
  float4 var = *(const float4*)variances;
  float t0 = dl.x * var.x, t1 = dl.y * var.y, t2 = dl.z * var.z, t3 = dl.w * var.w;
  float bw = expf(t3) * aw;
  float bh = expf(t2) * ah;
  float bcx = t1 * aw + acx;
  float bcy = t0 * ah + acy;
  float y1 = bcy - 0.5f * bh, x1 = bcx - 0.5f * bw;
  float y2 = bh + y1, x2 = bw + x1;
  sboxes[(size_t)b * NPOST + rank] = make_float4(y1, x1, y2, x2);
  sscores[(size_t)b * NPOST + rank] = score;
}

// ---------------- K3: pairwise IoU, TRANSPOSED (lower-tri) bitmask -----------
__global__ __launch_bounds__(256) void k_mask(const float4* __restrict__ sboxes,
                                              ull* __restrict__ maskT) {
  int b = blockIdx.x / 63, tile = blockIdx.x % 63;
  __shared__ float4 bx[NPOST];               // 16KB
  for (int j = threadIdx.x; j < NPOST; j += 256) bx[j] = sboxes[(size_t)b * NPOST + j];
  __syncthreads();
  int il = threadIdx.x >> 4, w = threadIdx.x & 15;
  int i = tile * 16 + il;
  if (i < NPOST) {
    ull bits = 0;
    if ((w << 6) < i) {                      // some j = w*64+jb can be < i
      float4 bi = bx[i];
      float ay1 = bi.x, ax1 = bi.y, ay2 = bi.z, ax2 = bi.w;
      float areai = (ay2 - ay1) * (ax2 - ax1);
      for (int jj = 0; jj < 64; ++jj) {
        int jb = (jj + w) & 63;              // skew to dodge LDS bank conflicts
        int j = (w << 6) + jb;
        if (j < i) {                         // lower-tri: rows j that suppress col i
          float4 bj = bx[j];
          float areaj = (bj.z - bj.x) * (bj.w - bj.y);
          float iy1 = fmaxf(ay1, bj.x), ix1 = fmaxf(ax1, bj.y);
          float iy2 = fminf(ay2, bj.z), ix2 = fminf(ax2, bj.w);
          float inter = fmaxf(iy2 - iy1, 0.f) * fmaxf(ix2 - ix1, 0.f);
          float uni = areai + areaj - inter;
          float iou = inter / fmaxf(uni, 1e-9f);
          if (iou > 0.7f) bits |= (1ull << jb);
        }
      }
    }
    maskT[((size_t)b * NPOST + i) * 16 + w] = bits;   // always write (nms reads)
  }
}

// ---------------- K4: greedy NMS, 4-slot LDS ring pipeline -------------------
// Wave 0 runs the rolled ballot chain reading columns from an LDS ring slot;
// waves 1-3 prefetch phase w+3's 64 columns (512x ulonglong2, coalesced) into
// the ring during phase w. One __syncthreads per phase; slot r/w disjoint.
// No u64 register arrays in the chain path -> no spill; small code -> no I$
// streaming; loads 3 phases ahead -> latency fully hidden.
__global__ __launch_bounds__(256, 1) void k_nms(const ull* __restrict__ maskT,
                                                const float4* __restrict__ sboxes,
                                                const float* __restrict__ sscores,
                                                float* __restrict__ out) {
  int b = blockIdx.x;
  __shared__ ull mt[4][64 * CSTRIDE];        // 34.8KB ring
  __shared__ ull keep_lds[16];
  __shared__ int pref[17];
  int tid = threadIdx.x;
  const ull* MT = maskT + (size_t)b * NPOST * 16;

  // prologue: stage phases 0..2 into slots 0..2 (all 256 threads, 6 ul2 each)
#pragma unroll
  for (int r = 0; r < 6; ++r) {
    int idx = tid + 256 * r;                 // 0..1535
    int tw = idx >> 9;                       // phase 0..2
    int rem = idx & 511;
    int col = rem >> 3, pair = rem & 7;
    ulonglong2 v = *(const ulonglong2*)(MT + (size_t)(tw * 64 + col) * 16 + pair * 2);
    mt[tw][col * CSTRIDE + pair * 2] = v.x;
    mt[tw][col * CSTRIDE + pair * 2 + 1] = v.y;
  }
  __syncthreads();

#pragma unroll 1
  for (int w = 0; w < 16; ++w) {
    if (tid < 64) {                          // wave 0: chain for phase w
      int lane = tid;
      const ull* col = &mt[w & 3][lane * CSTRIDE];
      ull acc = 0;
#pragma unroll
      for (int k = 0; k < 15; ++k)
        acc |= (k < w) ? (col[k] & keep_lds[k]) : 0ull;
      ull rm0 = (w == 0) ? 0ull : __ballot(acc != 0ull);
      ull qT = col[w];                       // LDS load, runtime offset (fine)
      unsigned qlo = (unsigned)qT, qhi = (unsigned)(qT >> 32);

      ull kmask = 0, supp = rm0;
#pragma unroll
      for (int bt = 0; bt < 4; ++bt) {
        ull rows[16];
        unsigned qd = (bt < 2) ? qlo : qhi;
#pragma unroll
        for (int r = 0; r < 16; ++r)
          rows[r] = __ballot(((qd >> ((bt & 1) * 16 + r)) & 1u) != 0u);
#pragma unroll
        for (int r = 0; r < 16; ++r) {
          int rr = bt * 16 + r;
          bool kp = ((supp >> rr) & 1ull) == 0ull;
          kmask |= kp ? (1ull << rr) : 0ull;
          supp  |= kp ? rows[r] : 0ull;
        }
      }
      if (w == 15) kmask &= (1ull << 40) - 1;   // boxes 1000..1023 invalid
      if (lane == 0) keep_lds[w] = kmask;
    } else if (w + 3 < 16) {                 // waves 1-3: prefetch phase w+3
      int tw = w + 3, slot = tw & 3;
      int t = tid - 64;                      // 0..191
#pragma unroll
      for (int r = 0; r < 3; ++r) {
        int idx = t + 192 * r;               // 0..575
        if (idx < 512) {
          int col = idx >> 3, pair = idx & 7;
          int gc = tw * 64 + col; if (gc > NPOST - 1) gc = NPOST - 1;
          ulonglong2 v = *(const ulonglong2*)(MT + (size_t)gc * 16 + pair * 2);
          mt[slot][col * CSTRIDE + pair * 2] = v.x;
          mt[slot][col * CSTRIDE + pair * 2 + 1] = v.y;
        }
      }
    }
    __syncthreads();
  }

  if (tid == 0) {
    int a = 0;
    for (int w = 0; w < 16; ++w) { pref[w] = a; a += __popcll(keep_lds[w]); }
    pref[16] = a;
  }
  __syncthreads();

  int total = pref[16];
  float4* ob = (float4*)out;                 // boxes: 16*1000 float4
  float* os = out + (size_t)NB * NPOST * 4;  // scores: 16*1000 floats
  for (int r = tid; r < NPOST; r += 256) {
    if (r >= total) {
      ob[(size_t)b * NPOST + r] = make_float4(0.f, 0.f, 0.f, 0.f);
      os[(size_t)b * NPOST + r] = 0.f;
    }
  }
  for (int r = tid; r < NPOST; r += 256) {
    int w = r >> 6, bb = r & 63;
    ull kw = keep_lds[w];
    if ((kw >> bb) & 1ull) {
      int pos = pref[w] + __popcll(bb ? (kw & ((1ull << bb) - 1)) : 0ull);
      ob[(size_t)b * NPOST + pos] = sboxes[(size_t)b * NPOST + r];
      os[(size_t)b * NPOST + pos] = sscores[(size_t)b * NPOST + r];
    }
  }
}

extern "C" void kernel_launch(void* const* d_in, const int* in_sizes, int n_in,
                              void* d_out, int out_size, void* d_ws, size_t ws_size,
                              hipStream_t stream) {
  const float* deltas    = (const float*)d_in[0];
  const float* labels    = (const float*)d_in[1];
  const float* anchors   = (const float*)d_in[2];
  const float* variances = (const float*)d_in[3];

  char* ws = (char*)d_ws;
  ull*     cand    = (ull*)(ws + OFF_CAND);
  ull*     maskT   = (ull*)(ws + OFF_MASK);
  float2*  partial = (float2*)(ws + OFF_PART);
  float4*  sboxes  = (float4*)(ws + OFF_SBOX);
  float*   sscores = (float*)(ws + OFF_SSCORE);

  k_select<<<NB * 16, 1024, 0, stream>>>(labels, cand, partial);
  k_rank_emit<<<NB * 4, 512, 0, stream>>>(cand, partial, labels, deltas,
                                          (const float4*)anchors, variances,
                                          sboxes, sscores);
  k_mask<<<NB * 63, 256, 0, stream>>>(sboxes, maskT);
  k_nms<<<NB, 256, 0, stream>>>(maskT, sboxes, sscores, (float*)d_out);
}

// Round 20
// 54.513 us; speedup vs baseline: 1.8390x; 1.6005x over previous
//
#include <hip/hip_runtime.h>

typedef unsigned long long ull;

#define NA 147456
#define NB 16
#define NBINS 16384        // top-14 bits of monotonic key
#define CAND_CAP 2048
#define SEG 128
#define NPOST 1000

// ws layout (bytes)
#define OFF_CAND    0                    // 16*2048*8    = 262144
#define OFF_MASK    262144               // 16*1000*16*8 = 2048000 (maskT)
#define OFF_PART    2310144              // 256*8        = 2048
#define OFF_SBOX    2312192              // 16*1000*16   = 256000
#define OFF_SSCORE  2568192              // 16*1000*4    = 64000

__device__ __forceinline__ unsigned mkey(float f) {
  unsigned u = __float_as_uint(f);
  return u ^ ((unsigned)((int)u >> 31) | 0x80000000u);  // monotonic: bigger float -> bigger key
}

// ---------------- K1: fused softmax-reduce + LOCAL top-128 select ------------
__global__ __launch_bounds__(1024) void k_select(const float* __restrict__ labels,
                                                 ull* __restrict__ cand,
                                                 float2* __restrict__ partial) {
  int b = blockIdx.x >> 4, blk = blockIdx.x & 15;
  __shared__ unsigned lh[NBINS];           // 64KB
  __shared__ ull sb[256];
  __shared__ float2 wlds[16];
  __shared__ unsigned wsums[16];
  __shared__ unsigned cntT;
  __shared__ int Tlds;
  int tid = threadIdx.x;
  int lane = tid & 63, wid = tid >> 6;
  for (int i = tid; i < NBINS; i += 1024) lh[i] = 0;
  if (tid < 256) sb[tid] = 0ULL;
  if (tid == 0) cntT = 0;
  __syncthreads();

  const int chunk = NA / 16;               // 9216 floats = 2304 float4
  const float4* row4 = (const float4*)(labels + (size_t)b * NA + blk * chunk);

  float4 v0 = row4[tid];
  float4 v1 = row4[tid + 1024];
  bool extra = tid < 256;
  float4 v2 = extra ? row4[tid + 2048] : make_float4(0.f, 0.f, 0.f, 0.f);

  atomicAdd(&lh[mkey(v0.x) >> 18], 1u);
  atomicAdd(&lh[mkey(v0.y) >> 18], 1u);
  atomicAdd(&lh[mkey(v0.z) >> 18], 1u);
  atomicAdd(&lh[mkey(v0.w) >> 18], 1u);
  atomicAdd(&lh[mkey(v1.x) >> 18], 1u);
  atomicAdd(&lh[mkey(v1.y) >> 18], 1u);
  atomicAdd(&lh[mkey(v1.z) >> 18], 1u);
  atomicAdd(&lh[mkey(v1.w) >> 18], 1u);
  if (extra) {
    atomicAdd(&lh[mkey(v2.x) >> 18], 1u);
    atomicAdd(&lh[mkey(v2.y) >> 18], 1u);
    atomicAdd(&lh[mkey(v2.z) >> 18], 1u);
    atomicAdd(&lh[mkey(v2.w) >> 18], 1u);
  }

  float m = fmaxf(fmaxf(fmaxf(v0.x, v0.y), fmaxf(v0.z, v0.w)),
                  fmaxf(fmaxf(v1.x, v1.y), fmaxf(v1.z, v1.w)));
  if (extra) m = fmaxf(m, fmaxf(fmaxf(v2.x, v2.y), fmaxf(v2.z, v2.w)));
  float s = expf(v0.x - m) + expf(v0.y - m) + expf(v0.z - m) + expf(v0.w - m)
          + expf(v1.x - m) + expf(v1.y - m) + expf(v1.z - m) + expf(v1.w - m);
  if (extra)
    s += expf(v2.x - m) + expf(v2.y - m) + expf(v2.z - m) + expf(v2.w - m);
  for (int off = 32; off > 0; off >>= 1) {
    float m2 = __shfl_down(m, off);
    float s2 = __shfl_down(s, off);
    float M = fmaxf(m, m2);
    s = s * expf(m - M) + s2 * expf(m2 - M);
    m = M;
  }
  if (lane == 0) wlds[wid] = make_float2(m, s);
  __syncthreads();                         // hist complete + wlds complete
  if (tid == 0) {
    float mm = -INFINITY, ss = 0.f;
    for (int i = 0; i < 16; ++i) {
      float2 p = wlds[i];
      float M = fmaxf(mm, p.x);
      ss = ss * expf(mm - M) + p.y * expf(p.x - M);
      mm = M;
    }
    partial[blockIdx.x] = make_float2(mm, ss);
  }

  // descending scan: thread t owns ranks [t*16, t*16+16)
  unsigned lsum = 0;
  unsigned lbin[16];
#pragma unroll
  for (int q = 0; q < 16; ++q) {
    lbin[q] = lh[NBINS - 1 - (tid * 16 + q)];
    lsum += lbin[q];
  }
  unsigned p = lsum;                       // wave inclusive prefix
  for (int d = 1; d < 64; d <<= 1) {
    unsigned t = __shfl_up(p, d);
    if (lane >= d) p += t;
  }
  if (lane == 63) wsums[wid] = p;
  __syncthreads();
  unsigned wexcl = 0;
#pragma unroll
  for (int w = 0; w < 16; ++w) wexcl += (w < wid) ? wsums[w] : 0u;
  unsigned excl = wexcl + p - lsum;
  unsigned incl = excl + lsum;
  if (excl < SEG && incl >= SEG) {         // crossing thread: find T
    unsigned running = excl;
#pragma unroll
    for (int q = 0; q < 16; ++q) {
      unsigned c = lbin[q];
      if (running < SEG && running + c >= SEG) Tlds = NBINS - 1 - (tid * 16 + q);
      running += c;
    }
  }
  __syncthreads();
  unsigned T = (unsigned)Tlds;

  // compact all elements with bin >= T (128..~137 of them) into sb
  {
    float vals[12] = {v0.x, v0.y, v0.z, v0.w, v1.x, v1.y, v1.z, v1.w,
                      v2.x, v2.y, v2.z, v2.w};
    int nv = extra ? 12 : 8;
    for (int c = 0; c < nv; ++c) {
      unsigned kk = mkey(vals[c]);
      if ((kk >> 18) >= T) {
        unsigned pos = atomicAdd(&cntT, 1u);
        int f4i = (c < 4) ? tid : (c < 8) ? (tid + 1024) : (tid + 2048);
        unsigned idx = (unsigned)(blk * chunk + f4i * 4 + (c & 3));
        if (pos < 256) sb[pos] = ((ull)kk << 32) | (unsigned)~idx;
      }
    }
  }
  __syncthreads();

  // wave 0: register bitonic sort of 256 (4 elems/lane), no barriers
  if (tid < 64) {
    ull v[4];
#pragma unroll
    for (int r = 0; r < 4; ++r) v[r] = sb[tid * 4 + r];
#pragma unroll
    for (int k = 2; k <= 256; k <<= 1) {
#pragma unroll
      for (int jl = 256; jl > 0; jl >>= 1) {
        int j = jl >> 1;
        if (j == 0 || j >= k) continue;    // j runs k/2..1
        if (j >= 4) {
          int lx = j >> 2;
#pragma unroll
          for (int r = 0; r < 4; ++r) {
            ull other = __shfl_xor(v[r], lx);
            int e = tid * 4 + r;
            bool up = (e & k) == 0;
            bool lower = (e & j) == 0;
            bool keep_max = (lower == up);
            bool gt = v[r] > other;
            v[r] = (keep_max == gt) ? v[r] : other;
          }
        } else {
#pragma unroll
          for (int r = 0; r < 4; ++r) {
            int rp = r ^ j;
            if (rp > r) {
              int e = tid * 4 + r;
              bool up = (e & k) == 0;
              ull a = v[r], c2 = v[rp];
              if (up ? (a < c2) : (a > c2)) { v[r] = c2; v[rp] = a; }
            }
          }
        }
      }
    }
    if (tid < 32) {
      ull* cb = cand + (size_t)b * CAND_CAP + blk * SEG;
#pragma unroll
      for (int r = 0; r < 4; ++r) cb[tid * 4 + r] = v[r];
    }
  }
}

// ---------------- K2: exact rank via binary search + (m,S) finalize ----------
__global__ __launch_bounds__(512) void k_rank_emit(const ull* __restrict__ cand,
                                                   const float2* __restrict__ partial,
                                                   const float* __restrict__ labels,
                                                   const float* __restrict__ deltas,
                                                   const float4* __restrict__ anchors,
                                                   const float* __restrict__ variances,
                                                   float4* __restrict__ sboxes,
                                                   float* __restrict__ sscores) {
  int b = blockIdx.x >> 2, part = blockIdx.x & 3;
  __shared__ ull sd[CAND_CAP];
  __shared__ float2 msld;
  for (int i = threadIdx.x; i < CAND_CAP; i += 512)
    sd[i] = cand[(size_t)b * CAND_CAP + i];  // 16 sorted (desc) 128-runs
  if (threadIdx.x == 0) {
    float m = -INFINITY, s = 0.f;
    for (int i = 0; i < 16; ++i) {
      float2 pp = partial[b * 16 + i];
      float M = fmaxf(m, pp.x);
      s = s * expf(m - M) + pp.y * expf(pp.x - M);
      m = M;
    }
    msld = make_float2(m, s);
  }
  __syncthreads();

  ull x = sd[part * 512 + threadIdx.x];
  int rank = 0;
#pragma unroll
  for (int t = 0; t < 16; ++t) {
    const ull* run = &sd[t << 7];
    int p = 0;
    if (run[p + 63] > x) p += 64;
    if (run[p + 31] > x) p += 32;
    if (run[p + 15] > x) p += 16;
    if (run[p + 7]  > x) p += 8;
    if (run[p + 3]  > x) p += 4;
    if (run[p + 1]  > x) p += 2;
    if (run[p]      > x) p += 1;
    rank += p;
  }
  if (rank >= NPOST) return;

  unsigned idx = ~(unsigned)(x & 0xFFFFFFFFu);
  float2 mt = msld;
  float lab = labels[(size_t)b * NA + idx];
  float score = expf(lab - mt.x) / mt.y;

  float4 an = anchors[idx];                  // [y1,x1,y2,x2]
  float aw = an.w - an.y;
  float ah = an.z - an.x;
  float acx = an.y + 0.5f * aw;
  float acy = an.x + 0.5f * ah;
  float4 dl = *(const float4*)(deltas + ((size_t)b * NA + idx) * 4);
  float4 var = *(const float4*)variances;
  float t0 = dl.x * var.x, t1 = dl.y * var.y, t2 = dl.z * var.z, t3 = dl.w * var.w;
  float bw = expf(t3) * aw;
  float bh = expf(t2) * ah;
  float bcx = t1 * aw + acx;
  float bcy = t0 * ah + acy;
  float y1 = bcy - 0.5f * bh, x1 = bcx - 0.5f * bw;
  float y2 = bh + y1, x2 = bw + x1;
  sboxes[(size_t)b * NPOST + rank] = make_float4(y1, x1, y2, x2);
  sscores[(size_t)b * NPOST + rank] = score;
}

// ---------------- K3: pairwise IoU, TRANSPOSED (lower-tri) bitmask -----------
__global__ __launch_bounds__(256) void k_mask(const float4* __restrict__ sboxes,
                                              ull* __restrict__ maskT) {
  int b = blockIdx.x / 63, tile = blockIdx.x % 63;
  __shared__ float4 bx[NPOST];               // 16KB
  for (int j = threadIdx.x; j < NPOST; j += 256) bx[j] = sboxes[(size_t)b * NPOST + j];
  __syncthreads();
  int il = threadIdx.x >> 4, w = threadIdx.x & 15;
  int i = tile * 16 + il;
  if (i < NPOST) {
    ull bits = 0;
    if ((w << 6) < i) {                      // some j = w*64+jb can be < i
      float4 bi = bx[i];
      float ay1 = bi.x, ax1 = bi.y, ay2 = bi.z, ax2 = bi.w;
      float areai = (ay2 - ay1) * (ax2 - ax1);
      for (int jj = 0; jj < 64; ++jj) {
        int jb = (jj + w) & 63;              // skew to dodge LDS bank conflicts
        int j = (w << 6) + jb;
        if (j < i) {                         // lower-tri: rows j that suppress col i
          float4 bj = bx[j];
          float areaj = (bj.z - bj.x) * (bj.w - bj.y);
          float iy1 = fmaxf(ay1, bj.x), ix1 = fmaxf(ax1, bj.y);
          float iy2 = fminf(ay2, bj.z), ix2 = fminf(ax2, bj.w);
          float inter = fmaxf(iy2 - iy1, 0.f) * fmaxf(ix2 - ix1, 0.f);
          float uni = areai + areaj - inter;
          float iou = inter / fmaxf(uni, 1e-9f);
          if (iou > 0.7f) bits |= (1ull << jb);
        }
      }
    }
    maskT[((size_t)b * NPOST + i) * 16 + w] = bits;   // always write (nms reads)
  }
}

// ---------------- K4: greedy NMS via exact round-based fixpoint --------------
// keep[i] = !any(j<i conflicting & kept), evaluated as a monotone fixpoint:
// per round an undecided box becomes REMOVED if an earlier KEPT box conflicts
// (a!=0), KEPT if a==0 and no earlier UNDECIDED conflicts (b==0), else waits.
// Lowest undecided always decides -> terminates; result == greedy, exactly.
// thread = column, wave w = word w -> state update is one __ballot per wave.
// 16 waves of TLP, no register arrays, ~3-6 rounds expected on this data.
__global__ __launch_bounds__(1024, 1) void k_nms(const ull* __restrict__ maskT,
                                                 const float4* __restrict__ sboxes,
                                                 const float* __restrict__ sscores,
                                                 float* __restrict__ out) {
  int b = blockIdx.x;
  __shared__ ull kept[16], undec[16];
  __shared__ int remaining;
  __shared__ int pref[17];
  int tid = threadIdx.x;
  int wid = tid >> 6, lane = tid & 63;
  const ull* MT = maskT + (size_t)b * NPOST * 16;
  int c = tid < NPOST ? tid : NPOST - 1;     // clamp; gated by undec bit
  const ulonglong2* colp = (const ulonglong2*)(MT + (size_t)c * 16);

  if (tid < 16) {
    kept[tid] = 0ULL;
    undec[tid] = (tid == 15) ? ((1ull << 40) - 1) : ~0ull;
  }
  __syncthreads();

#pragma unroll 1
  for (int round = 0; round < 1024; ++round) {
    ull a = 0, bb = 0;
#pragma unroll
    for (int k = 0; k < 8; ++k) {
      ulonglong2 x = colp[k];
      a  |= (x.x & kept[2 * k]) | (x.y & kept[2 * k + 1]);
      bb |= (x.x & undec[2 * k]) | (x.y & undec[2 * k + 1]);
    }
    bool isundec = ((undec[wid] >> lane) & 1ull) != 0ull;
    bool nr = isundec && (a != 0ull);                  // removed now
    bool nk = isundec && (a == 0ull) && (bb == 0ull);  // kept now
    ull bk = __ballot(nk);
    ull bd = __ballot(nk || nr);
    __syncthreads();                       // snapshots consumed
    if (lane == 0) {
      kept[wid] |= bk;
      undec[wid] &= ~bd;
    }
    __syncthreads();                       // updates visible
    if (tid == 0) {
      int rem = 0;
      for (int k = 0; k < 16; ++k) rem += __popcll(undec[k]);
      remaining = rem;
    }
    __syncthreads();
    if (remaining == 0) break;
  }

  if (tid == 0) {
    int a2 = 0;
    for (int w = 0; w < 16; ++w) { pref[w] = a2; a2 += __popcll(kept[w]); }
    pref[16] = a2;
  }
  __syncthreads();

  int total = pref[16];
  float4* ob = (float4*)out;                 // boxes: 16*1000 float4
  float* os = out + (size_t)NB * NPOST * 4;  // scores: 16*1000 floats
  for (int r = tid; r < NPOST; r += 1024) {
    if (r >= total) {
      ob[(size_t)b * NPOST + r] = make_float4(0.f, 0.f, 0.f, 0.f);
      os[(size_t)b * NPOST + r] = 0.f;
    }
  }
  for (int r = tid; r < NPOST; r += 1024) {
    int w = r >> 6, bbit = r & 63;
    ull kw = kept[w];
    if ((kw >> bbit) & 1ull) {
      int pos = pref[w] + __popcll(bbit ? (kw & ((1ull << bbit) - 1)) : 0ull);
      ob[(size_t)b * NPOST + pos] = sboxes[(size_t)b * NPOST + r];
      os[(size_t)b * NPOST + pos] = sscores[(size_t)b * NPOST + r];
    }
  }
}

extern "C" void kernel_launch(void* const* d_in, const int* in_sizes, int n_in,
                              void* d_out, int out_size, void* d_ws, size_t ws_size,
                              hipStream_t stream) {
  const float* deltas    = (const float*)d_in[0];
  const float* labels    = (const float*)d_in[1];
  const float* anchors   = (const float*)d_in[2];
  const float* variances = (const float*)d_in[3];

  char* ws = (char*)d_ws;
  ull*     cand    = (ull*)(ws + OFF_CAND);
  ull*     maskT   = (ull*)(ws + OFF_MASK);
  float2*  partial = (float2*)(ws + OFF_PART);
  float4*  sboxes  = (float4*)(ws + OFF_SBOX);
  float*   sscores = (float*)(ws + OFF_SSCORE);

  k_select<<<NB * 16, 1024, 0, stream>>>(labels, cand, partial);
  k_rank_emit<<<NB * 4, 512, 0, stream>>>(cand, partial, labels, deltas,
                                          (const float4*)anchors, variances,
                                          sboxes, sscores);
  k_mask<<<NB * 63, 256, 0, stream>>>(sboxes, maskT);
  k_nms<<<NB, 1024, 0, stream>>>(maskT, sboxes, sscores, (float*)d_out);
}